// Round 1
// baseline (53.790 us; speedup 1.0000x reference)
//
#include <hip/hip_runtime.h>

#define C_IN  32
#define O_OUT 48
#define H_IN  96
#define W_IN  96
#define H_OUT 192
#define W_OUT 192
#define B_SZ  2

// Each block: one (b,o), 16x16 threads, each thread computes a 2x2 output quad.
// Even output row ho=2s uses taps i in {1,3} -> x rows {s, s-1}
// Odd  output row ho=2s+1 uses taps i in {0,2} -> x rows {s+1, s}
// Norm classes per axis: 0: ho==0 {1} | 1: even interior {1,3} | 2: odd interior {0,2} | 3: ho==191 {2}
__global__ __launch_bounds__(256) void nct_kernel(
    const float* __restrict__ x,      // [B,32,96,96]
    const float* __restrict__ weight, // [48,32,4,4]
    const float* __restrict__ bias,   // [48]
    float* __restrict__ out)          // [B,48,192,192]
{
    __shared__ float wl[C_IN][16];
    __shared__ float rn[C_IN][16];

    const int bo = blockIdx.z;
    const int b  = bo / O_OUT;
    const int o  = bo % O_OUT;

    const int tid = threadIdx.y * 16 + threadIdx.x;

    // stage weight[o] (512 floats) into LDS
    {
        const float* wsrc = weight + (size_t)o * (C_IN * 16);
        for (int i = tid; i < C_IN * 16; i += 256)
            ((float*)wl)[i] = wsrc[i];
    }
    __syncthreads();

    // reciprocal-norm table: rn[c][a*4+b] = 1 / sum_{i in I[a], j in I[b]} w[c][i][j]
    {
        const int IM[4] = {0b0010, 0b1010, 0b0101, 0b0100};
        for (int idx = tid; idx < C_IN * 16; idx += 256) {
            const int c  = idx >> 4;
            const int a  = (idx >> 2) & 3;
            const int bb = idx & 3;
            float ssum = 0.f;
            #pragma unroll
            for (int i = 0; i < 4; ++i) {
                if (!((IM[a] >> i) & 1)) continue;
                #pragma unroll
                for (int j = 0; j < 4; ++j) {
                    if (!((IM[bb] >> j) & 1)) continue;
                    ssum += wl[c][i * 4 + j];
                }
            }
            rn[c][(a << 2) + bb] = 1.0f / ssum;
        }
    }
    __syncthreads();

    const int s = blockIdx.y * 16 + threadIdx.y;  // input-row coord in [0,96)
    const int t = blockIdx.x * 16 + threadIdx.x;  // input-col coord in [0,96)

    const int clsh_e = (s == 0)        ? 0 : 1;
    const int clsh_o = (s == H_IN - 1) ? 3 : 2;
    const int clsw_e = (t == 0)        ? 0 : 1;
    const int clsw_o = (t == W_IN - 1) ? 3 : 2;

    const bool hm = (s >= 1);
    const bool hp = (s + 1 < H_IN);
    const bool wm = (t >= 1);
    const bool wp = (t + 1 < W_IN);

    const float* xb = x + (size_t)b * (C_IN * H_IN * W_IN) + s * W_IN + t;

    float a00 = 0.f, a01 = 0.f, a10 = 0.f, a11 = 0.f;

    #pragma unroll 4
    for (int c = 0; c < C_IN; ++c) {
        const float* xc = xb + c * (H_IN * W_IN);

        // 3x3 zero-padded neighborhood
        float x_mm = (hm && wm) ? xc[-W_IN - 1] : 0.f;
        float x_m0 = hm         ? xc[-W_IN]     : 0.f;
        float x_mp = (hm && wp) ? xc[-W_IN + 1] : 0.f;
        float x_0m = wm         ? xc[-1]        : 0.f;
        float x_00 =              xc[0];
        float x_0p = wp         ? xc[1]         : 0.f;
        float x_pm = (hp && wm) ? xc[W_IN - 1]  : 0.f;
        float x_p0 = hp         ? xc[W_IN]      : 0.f;
        float x_pp = (hp && wp) ? xc[W_IN + 1]  : 0.f;

        const float* w = wl[c];
        // (even row, even col): (i,j) in {1,3}x{1,3}
        float yee = x_00 * w[1*4+1] + x_0m * w[1*4+3] + x_m0 * w[3*4+1] + x_mm * w[3*4+3];
        // (even row, odd col): j in {0,2} -> cols {t+1, t}
        float yeo = x_0p * w[1*4+0] + x_00 * w[1*4+2] + x_mp * w[3*4+0] + x_m0 * w[3*4+2];
        // (odd row, even col): i in {0,2} -> rows {s+1, s}
        float yoe = x_p0 * w[0*4+1] + x_pm * w[0*4+3] + x_00 * w[2*4+1] + x_0m * w[2*4+3];
        // (odd row, odd col)
        float yoo = x_pp * w[0*4+0] + x_p0 * w[0*4+2] + x_0p * w[2*4+0] + x_00 * w[2*4+2];

        const float* r = rn[c];
        a00 += yee * r[(clsh_e << 2) + clsw_e];
        a01 += yeo * r[(clsh_e << 2) + clsw_o];
        a10 += yoe * r[(clsh_o << 2) + clsw_e];
        a11 += yoo * r[(clsh_o << 2) + clsw_o];
    }

    const float bv = bias[o];
    float* op = out + ((size_t)(b * O_OUT + o) * H_OUT + 2 * s) * W_OUT + 2 * t;
    *(float2*)(op)         = make_float2(a00 + bv, a01 + bv);
    *(float2*)(op + W_OUT) = make_float2(a10 + bv, a11 + bv);
}

extern "C" void kernel_launch(void* const* d_in, const int* in_sizes, int n_in,
                              void* d_out, int out_size, void* d_ws, size_t ws_size,
                              hipStream_t stream) {
    const float* x    = (const float*)d_in[0];
    const float* w    = (const float*)d_in[1];
    const float* bias = (const float*)d_in[2];
    float* out = (float*)d_out;

    dim3 block(16, 16, 1);
    dim3 grid(W_IN / 16, H_IN / 16, B_SZ * O_OUT);  // 6 x 6 x 96
    hipLaunchKernelGGL(nct_kernel, grid, block, 0, stream, x, w, bias, out);
}